// Round 4
// baseline (3466.114 us; speedup 1.0000x reference)
//
#include <hip/hip_runtime.h>

// Problem constants (from reference)
#define N_NODES 2048
#define C_CH    128
#define NIRR    9
#define E_EL    10
// dslot mapping: 0 -> l0 (d=0), 1..3 -> l1 (d=0..2)

// Symmetrized coupling tables (tiny - live in LDS during contraction):
//   us3: [s3(165 triples p<=q<=i)][16 = ds*4+k]
//   us2: [s2(45 pairs p<=q)][12 = ds*3+k]
//   us1: [p(9)][8 = ds*2+k]
#define NS3 165
#define NS2 45
#define US3_FLOATS (NS3 * 16)   // 2640
#define US2_FLOATS (NS2 * 12)   //  540
#define US1_FLOATS (9 * 8)      //   72

__global__ __launch_bounds__(64) void zero_cnt_kernel(int* __restrict__ cnt) {
    if (threadIdx.x < 16) cnt[threadIdx.x] = 0;
}

// Find each node's element (one-hot) and bucket node ids by element.
__global__ __launch_bounds__(256) void bucket_kernel(const float* __restrict__ y,
                                                     int* __restrict__ cnt,
                                                     int* __restrict__ lists) {
    int b = blockIdx.x * 256 + threadIdx.x;
    if (b >= N_NODES) return;
    int e = 0;
    #pragma unroll
    for (int k = 1; k < E_EL; k++)
        if (y[b * E_EL + k] > 0.5f) e = k;
    int pos = atomicAdd(&cnt[e], 1);
    lists[e * N_NODES + pos] = b;
}

// Symmetrize u3/u2/u1 over index-permutation orbits (monomial x_p x_q x_i is
// symmetric, so only sorted index tuples matter). Output is 3252 floats total.
__global__ __launch_bounds__(256) void build_sym_kernel(
    const float* __restrict__ u3_l0, const float* __restrict__ u2_l0, const float* __restrict__ u1_l0,
    const float* __restrict__ u3_l1, const float* __restrict__ u2_l1, const float* __restrict__ u1_l1,
    float* __restrict__ us3, float* __restrict__ us2, float* __restrict__ us1)
{
    int t = blockIdx.x * 256 + threadIdx.x;
    if (t < US3_FLOATS) {
        int s = t >> 4, dk = t & 15, ds = dk >> 2, k = dk & 3;
        int pp = 0, qq = 0, ii = 0, cntr = 0;
        for (int p = 0; p < 9; p++)
            for (int q = p; q < 9; q++)
                for (int i = q; i < 9; i++) {
                    if (cntr == s) { pp = p; qq = q; ii = i; }
                    cntr++;
                }
        const float* u = (ds == 0) ? u3_l0 : (u3_l1 + (ds - 1) * 2916);
        int perm[6][3] = {{pp,qq,ii},{pp,ii,qq},{qq,pp,ii},{qq,ii,pp},{ii,pp,qq},{ii,qq,pp}};
        float acc = 0.f;
        #pragma unroll
        for (int j = 0; j < 6; j++)
            acc += u[((perm[j][0] * 9 + perm[j][1]) * 9 + perm[j][2]) * 4 + k];
        float mult = (pp == qq && qq == ii) ? 6.f : ((pp == qq || qq == ii) ? 2.f : 1.f);
        us3[t] = acc / mult;
    } else if (t < US3_FLOATS + US2_FLOATS) {
        int t2 = t - US3_FLOATS;
        int s = t2 / 12, dk = t2 % 12, ds = dk / 3, k = dk % 3;
        int pp = 0, qq = 0, cntr = 0;
        for (int p = 0; p < 9; p++)
            for (int q = p; q < 9; q++) {
                if (cntr == s) { pp = p; qq = q; }
                cntr++;
            }
        const float* u = (ds == 0) ? u2_l0 : (u2_l1 + (ds - 1) * 243);
        float acc = u[(pp * 9 + qq) * 3 + k] + u[(qq * 9 + pp) * 3 + k];
        us2[t2] = (pp == qq) ? acc * 0.5f : acc;
    } else if (t < US3_FLOATS + US2_FLOATS + US1_FLOATS) {
        int t1 = t - US3_FLOATS - US2_FLOATS;
        int p = t1 >> 3, dk = t1 & 7, ds = dk >> 1, k = dk & 1;
        const float* u = (ds == 0) ? u1_l0 : (u1_l1 + (ds - 1) * 18);
        us1[t1] = u[p * 2 + k];
    }
}

#define ACC4(G, off, v4, X) \
    G[(off) + 0] += (v4).x * (X); G[(off) + 1] += (v4).y * (X); \
    G[(off) + 2] += (v4).z * (X); G[(off) + 3] += (v4).w * (X);

// Main contraction. grid = (512, E); block = 2 subs x 128 c, 4 nodes/block
// (2 per thread). Tables broadcast from LDS with compile-time offsets.
// Per (b,c): G3[ds,k] = sum_{p<=q<=i} us3[s,ds,k] * x_p x_q x_i  (etc.)
// then f[ds] = sum_k w3[e,k,c]*G3[ds,k] + w2*G2 + w1*G1.
__global__ __launch_bounds__(256) void contract_kernel(
    const float* __restrict__ x,
    const float* __restrict__ us3g, const float* __restrict__ us2g, const float* __restrict__ us1g,
    const float* __restrict__ w3_l0, const float* __restrict__ w2_l0, const float* __restrict__ w1_l0,
    const float* __restrict__ w3_l1, const float* __restrict__ w2_l1, const float* __restrict__ w1_l1,
    const int* __restrict__ cnt, const int* __restrict__ lists,
    float* __restrict__ fbuf)
{
    __shared__ float lus3[US3_FLOATS];
    __shared__ float lus2[US2_FLOATS];
    __shared__ float lus1[US1_FLOATS];
    int e = blockIdx.y;
    int count = cnt[e];
    int base0 = blockIdx.x * 4;
    if (base0 >= count) return;

    int tid = threadIdx.x;
    for (int i = tid; i < US3_FLOATS; i += 256) lus3[i] = us3g[i];
    for (int i = tid; i < US2_FLOATS; i += 256) lus2[i] = us2g[i];
    if (tid < US1_FLOATS) lus1[tid] = us1g[tid];
    __syncthreads();

    int c = tid & 127;
    int sub = tid >> 7;
    int base = base0 + sub * 2;

    int bnode[2];
    bool valid[2];
    #pragma unroll
    for (int j = 0; j < 2; j++) {
        int ii = base + j;
        valid[j] = (ii < count);
        bnode[j] = lists[e * N_NODES + (valid[j] ? ii : 0)];
    }

    float xv[2][9];
    #pragma unroll
    for (int j = 0; j < 2; j++) {
        const float* xp = x + ((size_t)bnode[j] * C_CH + c) * NIRR;
        #pragma unroll
        for (int i = 0; i < 9; i++) xv[j][i] = xp[i];
    }

    float G3[2][16], G2[2][12], G1[2][8];
    #pragma unroll
    for (int j = 0; j < 2; j++) {
        #pragma unroll
        for (int t = 0; t < 16; t++) G3[j][t] = 0.f;
        #pragma unroll
        for (int t = 0; t < 12; t++) G2[j][t] = 0.f;
        #pragma unroll
        for (int t = 0; t < 8; t++) G1[j][t] = 0.f;
    }

    const float4* U3 = (const float4*)lus3;   // [s3*4 + 0..3]
    const float4* U2 = (const float4*)lus2;   // [s2*3 + 0..2]
    const float4* U1 = (const float4*)lus1;   // [p*2 + 0..1]

    int s3 = 0, s2 = 0;
    #pragma unroll
    for (int p = 0; p < 9; p++) {
        {
            float4 a = U1[p * 2], b = U1[p * 2 + 1];
            #pragma unroll
            for (int j = 0; j < 2; j++) {
                float X = xv[j][p];
                ACC4(G1[j], 0, a, X);
                ACC4(G1[j], 4, b, X);
            }
        }
        #pragma unroll
        for (int q = p; q < 9; q++) {
            float pq[2] = { xv[0][p] * xv[0][q], xv[1][p] * xv[1][q] };
            {
                float4 a = U2[s2 * 3], b = U2[s2 * 3 + 1], d = U2[s2 * 3 + 2];
                #pragma unroll
                for (int j = 0; j < 2; j++) {
                    float X = pq[j];
                    ACC4(G2[j], 0, a, X);
                    ACC4(G2[j], 4, b, X);
                    ACC4(G2[j], 8, d, X);
                }
            }
            s2++;
            #pragma unroll
            for (int i = q; i < 9; i++) {
                float4 a = U3[s3 * 4], b = U3[s3 * 4 + 1];
                float4 d = U3[s3 * 4 + 2], f4 = U3[s3 * 4 + 3];
                #pragma unroll
                for (int j = 0; j < 2; j++) {
                    float X = pq[j] * xv[j][i];
                    ACC4(G3[j], 0, a, X);
                    ACC4(G3[j], 4, b, X);
                    ACC4(G3[j], 8, d, X);
                    ACC4(G3[j], 12, f4, X);
                }
                s3++;
            }
        }
    }

    // element weights (lane c): w3 (E,4,C), w2 (E,3,C), w1 (E,2,C)
    float w30[4], w31[4], w20[3], w21[3], w10[2], w11[2];
    #pragma unroll
    for (int k = 0; k < 4; k++) { w30[k] = w3_l0[(e * 4 + k) * 128 + c]; w31[k] = w3_l1[(e * 4 + k) * 128 + c]; }
    #pragma unroll
    for (int k = 0; k < 3; k++) { w20[k] = w2_l0[(e * 3 + k) * 128 + c]; w21[k] = w2_l1[(e * 3 + k) * 128 + c]; }
    #pragma unroll
    for (int k = 0; k < 2; k++) { w10[k] = w1_l0[(e * 2 + k) * 128 + c]; w11[k] = w1_l1[(e * 2 + k) * 128 + c]; }

    #pragma unroll
    for (int j = 0; j < 2; j++) {
        if (!valid[j]) continue;
        float f0 = 0.f;
        #pragma unroll
        for (int k = 0; k < 4; k++) f0 += w30[k] * G3[j][k];
        #pragma unroll
        for (int k = 0; k < 3; k++) f0 += w20[k] * G2[j][k];
        #pragma unroll
        for (int k = 0; k < 2; k++) f0 += w10[k] * G1[j][k];
        fbuf[((size_t)0 * N_NODES + bnode[j]) * C_CH + c] = f0;
        #pragma unroll
        for (int ds = 1; ds < 4; ds++) {
            float f = 0.f;
            #pragma unroll
            for (int k = 0; k < 4; k++) f += w31[k] * G3[j][ds * 4 + k];
            #pragma unroll
            for (int k = 0; k < 3; k++) f += w21[k] * G2[j][ds * 3 + k];
            #pragma unroll
            for (int k = 0; k < 2; k++) f += w11[k] * G1[j][ds * 2 + k];
            fbuf[((size_t)ds * N_NODES + bnode[j]) * C_CH + c] = f;
        }
    }
}

// Block-diagonal per-irrep channel mixing (o3.Linear) + skip connection.
__global__ __launch_bounds__(256) void linear_kernel(
    const float* __restrict__ fbuf,
    const float* __restrict__ w0, const float* __restrict__ w1,
    const float* __restrict__ sc, float* __restrict__ out)
{
    __shared__ float fs[4 * 8 * 128];  // 16 KB
    int b0 = blockIdx.x * 8;
    int tid = threadIdx.x;
    for (int idx = tid; idx < 4096; idx += 256) {
        int m = idx >> 10;
        int rem = idx & 1023;
        int nb = rem >> 7;
        int i = rem & 127;
        fs[idx] = fbuf[((size_t)m * N_NODES + b0 + nb) * 128 + i];
    }
    __syncthreads();

    int j = tid & 127;
    int g = tid >> 7;
    const float inv_sqrt_c = 0.08838834764831845f;  // 1/sqrt(128)

    #pragma unroll
    for (int mm = 0; mm < 2; mm++) {
        int m = g + mm * 2;  // covers dslots {0,2} / {1,3}
        const float* w = (m == 0) ? w0 : w1;
        float acc[8];
        #pragma unroll
        for (int nb = 0; nb < 8; nb++) acc[nb] = 0.f;
        for (int i = 0; i < 128; i++) {
            float wv = w[i * 128 + j];
            #pragma unroll
            for (int nb = 0; nb < 8; nb++) acc[nb] += fs[m * 1024 + nb * 128 + i] * wv;
        }
        int col = (m == 0) ? j : (128 + j * 3 + (m - 1));
        #pragma unroll
        for (int nb = 0; nb < 8; nb++) {
            int oi = (b0 + nb) * 512 + col;
            out[oi] = acc[nb] * inv_sqrt_c + sc[oi];
        }
    }
}

extern "C" void kernel_launch(void* const* d_in, const int* in_sizes, int n_in,
                              void* d_out, int out_size, void* d_ws, size_t ws_size,
                              hipStream_t stream) {
    const float* x     = (const float*)d_in[0];
    const float* y     = (const float*)d_in[1];
    const float* sc    = (const float*)d_in[2];
    const float* u3_l0 = (const float*)d_in[3];
    const float* u2_l0 = (const float*)d_in[4];
    const float* u1_l0 = (const float*)d_in[5];
    const float* w3_l0 = (const float*)d_in[6];
    const float* w2_l0 = (const float*)d_in[7];
    const float* w1_l0 = (const float*)d_in[8];
    const float* u3_l1 = (const float*)d_in[9];
    const float* u2_l1 = (const float*)d_in[10];
    const float* u1_l1 = (const float*)d_in[11];
    const float* w3_l1 = (const float*)d_in[12];
    const float* w2_l1 = (const float*)d_in[13];
    const float* w1_l1 = (const float*)d_in[14];
    const float* lw0   = (const float*)d_in[15];
    const float* lw1   = (const float*)d_in[16];
    float* out = (float*)d_out;

    // Workspace layout (floats): us3 | us2 | us1 | fbuf | cnt(int) | lists(int)
    float* us3  = (float*)d_ws;
    float* us2  = us3 + US3_FLOATS;
    float* us1  = us2 + US2_FLOATS;
    float* fbuf = us1 + US1_FLOATS;
    int*   cnt  = (int*)(fbuf + (size_t)4 * N_NODES * C_CH);
    int*   lists = cnt + 16;

    zero_cnt_kernel<<<1, 64, 0, stream>>>(cnt);
    bucket_kernel<<<N_NODES / 256, 256, 0, stream>>>(y, cnt, lists);
    build_sym_kernel<<<13, 256, 0, stream>>>(
        u3_l0, u2_l0, u1_l0, u3_l1, u2_l1, u1_l1, us3, us2, us1);
    contract_kernel<<<dim3(N_NODES / 4, E_EL), 256, 0, stream>>>(
        x, us3, us2, us1,
        w3_l0, w2_l0, w1_l0, w3_l1, w2_l1, w1_l1,
        cnt, lists, fbuf);
    linear_kernel<<<N_NODES / 8, 256, 0, stream>>>(fbuf, lw0, lw1, sc, out);
}

// Round 5
// 169.814 us; speedup vs baseline: 20.4112x; 20.4112x over previous
//
#include <hip/hip_runtime.h>

// Problem constants (from reference)
#define N_NODES 2048
#define C_CH    128
#define NIRR    9
#define E_EL    10
// dslot mapping: 0 -> l0 (d=0), 1..3 -> l1 (d=0..2)

// Symmetrized coupling tables (tiny, wave-uniform, scalar-loaded):
//   us3: [s3(165 triples p<=q<=i)][16 = ds*4+k]
//   us2: [s2(45 pairs p<=q)][12 = ds*3+k]
//   us1: [p(9)][8 = ds*2+k]
#define NS3 165
#define NS2 45
#define US3_FLOATS (NS3 * 16)   // 2640
#define US2_FLOATS (NS2 * 12)   //  540
#define US1_FLOATS (9 * 8)      //   72

__global__ __launch_bounds__(64) void zero_cnt_kernel(int* __restrict__ cnt) {
    if (threadIdx.x < 16) cnt[threadIdx.x] = 0;
}

// Find each node's element (one-hot) and bucket node ids by element.
__global__ __launch_bounds__(256) void bucket_kernel(const float* __restrict__ y,
                                                     int* __restrict__ cnt,
                                                     int* __restrict__ lists) {
    int b = blockIdx.x * 256 + threadIdx.x;
    if (b >= N_NODES) return;
    int e = 0;
    #pragma unroll
    for (int k = 1; k < E_EL; k++)
        if (y[b * E_EL + k] > 0.5f) e = k;
    int pos = atomicAdd(&cnt[e], 1);
    lists[e * N_NODES + pos] = b;
}

// Symmetrize u3/u2/u1 over index-permutation orbits (monomial x_p x_q x_i is
// symmetric, so only sorted index tuples matter). Output is 3252 floats total.
__global__ __launch_bounds__(256) void build_sym_kernel(
    const float* __restrict__ u3_l0, const float* __restrict__ u2_l0, const float* __restrict__ u1_l0,
    const float* __restrict__ u3_l1, const float* __restrict__ u2_l1, const float* __restrict__ u1_l1,
    float* __restrict__ us3, float* __restrict__ us2, float* __restrict__ us1)
{
    int t = blockIdx.x * 256 + threadIdx.x;
    if (t < US3_FLOATS) {
        int s = t >> 4, dk = t & 15, ds = dk >> 2, k = dk & 3;
        int pp = 0, qq = 0, ii = 0, cntr = 0;
        for (int p = 0; p < 9; p++)
            for (int q = p; q < 9; q++)
                for (int i = q; i < 9; i++) {
                    if (cntr == s) { pp = p; qq = q; ii = i; }
                    cntr++;
                }
        const float* u = (ds == 0) ? u3_l0 : (u3_l1 + (ds - 1) * 2916);
        int perm[6][3] = {{pp,qq,ii},{pp,ii,qq},{qq,pp,ii},{qq,ii,pp},{ii,pp,qq},{ii,qq,pp}};
        float acc = 0.f;
        #pragma unroll
        for (int j = 0; j < 6; j++)
            acc += u[((perm[j][0] * 9 + perm[j][1]) * 9 + perm[j][2]) * 4 + k];
        float mult = (pp == qq && qq == ii) ? 6.f : ((pp == qq || qq == ii) ? 2.f : 1.f);
        us3[t] = acc / mult;
    } else if (t < US3_FLOATS + US2_FLOATS) {
        int t2 = t - US3_FLOATS;
        int s = t2 / 12, dk = t2 % 12, ds = dk / 3, k = dk % 3;
        int pp = 0, qq = 0, cntr = 0;
        for (int p = 0; p < 9; p++)
            for (int q = p; q < 9; q++) {
                if (cntr == s) { pp = p; qq = q; }
                cntr++;
            }
        const float* u = (ds == 0) ? u2_l0 : (u2_l1 + (ds - 1) * 243);
        float acc = u[(pp * 9 + qq) * 3 + k] + u[(qq * 9 + pp) * 3 + k];
        us2[t2] = (pp == qq) ? acc * 0.5f : acc;
    } else if (t < US3_FLOATS + US2_FLOATS + US1_FLOATS) {
        int t1 = t - US3_FLOATS - US2_FLOATS;
        int p = t1 >> 3, dk = t1 & 7, ds = dk >> 1, k = dk & 1;
        const float* u = (ds == 0) ? u1_l0 : (u1_l1 + (ds - 1) * 18);
        us1[t1] = u[p * 2 + k];
    }
}

// Main contraction. grid = (1024, E); block = 2 nodes x 128 c; 1 node/thread.
// Table entries are wave-uniform with compile-time offsets -> compiler emits
// scalar s_load into SGPRs; each FMA is v_fmac vG, sU, vX (no VGPR pressure
// from the table). 36 accumulators + 9 xv per thread.
__global__ __launch_bounds__(256, 4) void contract_kernel(
    const float* __restrict__ x,
    const float* __restrict__ us3, const float* __restrict__ us2, const float* __restrict__ us1,
    const float* __restrict__ w3_l0, const float* __restrict__ w2_l0, const float* __restrict__ w1_l0,
    const float* __restrict__ w3_l1, const float* __restrict__ w2_l1, const float* __restrict__ w1_l1,
    const int* __restrict__ cnt, const int* __restrict__ lists,
    float* __restrict__ fbuf)
{
    int e = blockIdx.y;
    int count = cnt[e];
    int tid = threadIdx.x;
    int c = tid & 127;
    int ii = blockIdx.x * 2 + (tid >> 7);
    if (ii >= count) return;
    int bnode = lists[e * N_NODES + ii];

    float xv[9];
    {
        const float* xp = x + ((size_t)bnode * C_CH + c) * NIRR;
        #pragma unroll
        for (int i = 0; i < 9; i++) xv[i] = xp[i];
    }

    float G3[16], G2[12], G1[8];
    #pragma unroll
    for (int t = 0; t < 16; t++) G3[t] = 0.f;
    #pragma unroll
    for (int t = 0; t < 12; t++) G2[t] = 0.f;
    #pragma unroll
    for (int t = 0; t < 8; t++) G1[t] = 0.f;

    int s3 = 0, s2 = 0;
    #pragma unroll
    for (int p = 0; p < 9; p++) {
        float xp = xv[p];
        #pragma unroll
        for (int k = 0; k < 8; k++) G1[k] += us1[p * 8 + k] * xp;
        #pragma unroll
        for (int q = p; q < 9; q++) {
            float pq = xp * xv[q];
            #pragma unroll
            for (int k = 0; k < 12; k++) G2[k] += us2[s2 * 12 + k] * pq;
            s2++;
            #pragma unroll
            for (int i = q; i < 9; i++) {
                float X = pq * xv[i];
                #pragma unroll
                for (int k = 0; k < 16; k++) G3[k] += us3[s3 * 16 + k] * X;
                s3++;
            }
        }
    }

    // element weights (lane c): w3 (E,4,C), w2 (E,3,C), w1 (E,2,C)
    float f0 = 0.f;
    #pragma unroll
    for (int k = 0; k < 4; k++) f0 += w3_l0[(e * 4 + k) * 128 + c] * G3[k];
    #pragma unroll
    for (int k = 0; k < 3; k++) f0 += w2_l0[(e * 3 + k) * 128 + c] * G2[k];
    #pragma unroll
    for (int k = 0; k < 2; k++) f0 += w1_l0[(e * 2 + k) * 128 + c] * G1[k];
    fbuf[((size_t)bnode) * C_CH + c] = f0;

    float w31[4], w21[3], w11[2];
    #pragma unroll
    for (int k = 0; k < 4; k++) w31[k] = w3_l1[(e * 4 + k) * 128 + c];
    #pragma unroll
    for (int k = 0; k < 3; k++) w21[k] = w2_l1[(e * 3 + k) * 128 + c];
    #pragma unroll
    for (int k = 0; k < 2; k++) w11[k] = w1_l1[(e * 2 + k) * 128 + c];
    #pragma unroll
    for (int ds = 1; ds < 4; ds++) {
        float f = 0.f;
        #pragma unroll
        for (int k = 0; k < 4; k++) f += w31[k] * G3[ds * 4 + k];
        #pragma unroll
        for (int k = 0; k < 3; k++) f += w21[k] * G2[ds * 3 + k];
        #pragma unroll
        for (int k = 0; k < 2; k++) f += w11[k] * G1[ds * 2 + k];
        fbuf[((size_t)ds * N_NODES + bnode) * C_CH + c] = f;
    }
}

// Block-diagonal per-irrep channel mixing (o3.Linear) + skip connection.
__global__ __launch_bounds__(256) void linear_kernel(
    const float* __restrict__ fbuf,
    const float* __restrict__ w0, const float* __restrict__ w1,
    const float* __restrict__ sc, float* __restrict__ out)
{
    __shared__ float fs[4 * 8 * 128];  // 16 KB
    int b0 = blockIdx.x * 8;
    int tid = threadIdx.x;
    for (int idx = tid; idx < 4096; idx += 256) {
        int m = idx >> 10;
        int rem = idx & 1023;
        int nb = rem >> 7;
        int i = rem & 127;
        fs[idx] = fbuf[((size_t)m * N_NODES + b0 + nb) * 128 + i];
    }
    __syncthreads();

    int j = tid & 127;
    int g = tid >> 7;
    const float inv_sqrt_c = 0.08838834764831845f;  // 1/sqrt(128)

    #pragma unroll
    for (int mm = 0; mm < 2; mm++) {
        int m = g + mm * 2;  // covers dslots {0,2} / {1,3}
        const float* w = (m == 0) ? w0 : w1;
        float acc[8];
        #pragma unroll
        for (int nb = 0; nb < 8; nb++) acc[nb] = 0.f;
        for (int i = 0; i < 128; i++) {
            float wv = w[i * 128 + j];
            #pragma unroll
            for (int nb = 0; nb < 8; nb++) acc[nb] += fs[m * 1024 + nb * 128 + i] * wv;
        }
        int col = (m == 0) ? j : (128 + j * 3 + (m - 1));
        #pragma unroll
        for (int nb = 0; nb < 8; nb++) {
            int oi = (b0 + nb) * 512 + col;
            out[oi] = acc[nb] * inv_sqrt_c + sc[oi];
        }
    }
}

extern "C" void kernel_launch(void* const* d_in, const int* in_sizes, int n_in,
                              void* d_out, int out_size, void* d_ws, size_t ws_size,
                              hipStream_t stream) {
    const float* x     = (const float*)d_in[0];
    const float* y     = (const float*)d_in[1];
    const float* sc    = (const float*)d_in[2];
    const float* u3_l0 = (const float*)d_in[3];
    const float* u2_l0 = (const float*)d_in[4];
    const float* u1_l0 = (const float*)d_in[5];
    const float* w3_l0 = (const float*)d_in[6];
    const float* w2_l0 = (const float*)d_in[7];
    const float* w1_l0 = (const float*)d_in[8];
    const float* u3_l1 = (const float*)d_in[9];
    const float* u2_l1 = (const float*)d_in[10];
    const float* u1_l1 = (const float*)d_in[11];
    const float* w3_l1 = (const float*)d_in[12];
    const float* w2_l1 = (const float*)d_in[13];
    const float* w1_l1 = (const float*)d_in[14];
    const float* lw0   = (const float*)d_in[15];
    const float* lw1   = (const float*)d_in[16];
    float* out = (float*)d_out;

    // Workspace layout (floats): us3 | us2 | us1 | fbuf | cnt(int) | lists(int)
    float* us3  = (float*)d_ws;
    float* us2  = us3 + US3_FLOATS;
    float* us1  = us2 + US2_FLOATS;
    float* fbuf = us1 + US1_FLOATS;
    int*   cnt  = (int*)(fbuf + (size_t)4 * N_NODES * C_CH);
    int*   lists = cnt + 16;

    zero_cnt_kernel<<<1, 64, 0, stream>>>(cnt);
    bucket_kernel<<<N_NODES / 256, 256, 0, stream>>>(y, cnt, lists);
    build_sym_kernel<<<13, 256, 0, stream>>>(
        u3_l0, u2_l0, u1_l0, u3_l1, u2_l1, u1_l1, us3, us2, us1);
    contract_kernel<<<dim3(N_NODES / 2, E_EL), 256, 0, stream>>>(
        x, us3, us2, us1,
        w3_l0, w2_l0, w1_l0, w3_l1, w2_l1, w1_l1,
        cnt, lists, fbuf);
    linear_kernel<<<N_NODES / 8, 256, 0, stream>>>(fbuf, lw0, lw1, sc, out);
}